// Round 2
// baseline (75.463 us; speedup 1.0000x reference)
//
#include <hip/hip_runtime.h>

#define B_SZ 32
#define A_SZ 64
#define P_TOTAL 16320
#define NBLK_P 64               // ceil(16320/256)
#define INF_C 100000000.0f

// One thread per (b, p). Scans all A=64 gt boxes (argmin over center-dist with
// validity gating), computes giou*cness, block-reduces, writes one partial
// (sum_giou, npos) per block into d_ws. No atomics, no memset needed.
__global__ __launch_bounds__(256) void fcos_main_kernel(
    const float* __restrict__ reg_preds,   // [B, P, 2]
    const float* __restrict__ positions,   // [B, P]
    const float* __restrict__ gt_boxes,    // [B, A, 2]
    const float* __restrict__ mi,          // [P, 2]
    float2* __restrict__ partial)          // [B, NBLK_P] (sum_giou, npos)
{
    const int b = blockIdx.y;
    const int p = blockIdx.x * blockDim.x + threadIdx.x;

    // Stage this video's gt boxes in LDS as float2 (512 B).
    __shared__ float2 s_box[A_SZ];
    if (threadIdx.x < A_SZ) {
        s_box[threadIdx.x] =
            reinterpret_cast<const float2*>(gt_boxes)[b * A_SZ + threadIdx.x];
    }
    __syncthreads();

    float contrib = 0.0f;
    float mval = 0.0f;

    if (p < P_TOTAL) {
        const float  pos  = positions[b * P_TOTAL + p];
        const float2 mi2  = reinterpret_cast<const float2*>(mi)[p];
        const float  lo   = mi2.x;
        const float  hi   = mi2.y;

        float best_dist = 3.0e38f;   // > any achievable dist
        float l_t = 0.0f, r_t = 0.0f;
        bool  is_pos = false;

        #pragma unroll 8
        for (int a = 0; a < A_SZ; ++a) {
            const float2 box = s_box[a];          // broadcast ds_read_b64
            const float gs = box.x;
            const float ge = box.y;
            const float l  = pos - gs;
            const float r  = ge - pos;
            const float cmin = fminf(l, r);
            const float cmax = fmaxf(l, r);
            const bool valid = (cmin > 0.0f) && (cmax >= lo) && (cmax < hi);
            // EXACT reference arithmetic: center = 0.5*(l+r)+gs (not 0.5*(gs+ge))
            const float center = valid ? (0.5f * (l + r) + gs) : INF_C;
            const float dist   = fabsf(pos - center);
            // strict < keeps FIRST index on ties == jnp.argmin semantics
            if (dist < best_dist) { best_dist = dist; l_t = l; r_t = r; }
            is_pos = is_pos || valid;
        }

        if (!is_pos) { l_t = 0.0f; r_t = 0.0f; }

        const float ratio = fminf(l_t, r_t) / fmaxf(fmaxf(l_t, r_t), 1e-8f);
        const float cness = is_pos ? sqrtf(fmaxf(ratio, 0.0f)) : 0.0f;

        const float2 rp = reinterpret_cast<const float2*>(reg_preds)[b * P_TOTAL + p];
        const float pmin = pos - rp.x;
        const float pmax = pos + rp.y;
        const float gmin = pos - l_t;
        const float gmax = pos + r_t;

        const float overlap = fmaxf(fminf(pmax, gmax) - fmaxf(pmin, gmin), 0.0f);
        const float uni     = fmaxf((pmax - pmin + 1.0f) + (gmax - gmin + 1.0f) - overlap, 1e-4f);
        const float ious    = overlap / uni;
        const float enclose = fmaxf(fmaxf(pmax, gmax) - fminf(pmin, gmin), 1e-4f);
        float giou = 1.0f - ious + (enclose - uni) / enclose;
        giou = fminf(fmaxf(giou, -1.0f), 1.0f) * cness;

        mval    = is_pos ? 1.0f : 0.0f;
        contrib = giou;   // giou already scaled by cness; masked below
        contrib *= mval;
    }

    // ---- block reduction: 4 waves of 64 ----
    const int lane = threadIdx.x & 63;
    const int wid  = threadIdx.x >> 6;

    #pragma unroll
    for (int off = 32; off > 0; off >>= 1) {
        contrib += __shfl_down(contrib, off, 64);
        mval    += __shfl_down(mval,    off, 64);
    }

    __shared__ float s_c[4];
    __shared__ float s_m[4];
    if (lane == 0) { s_c[wid] = contrib; s_m[wid] = mval; }
    __syncthreads();

    if (threadIdx.x == 0) {
        float2 out2;
        out2.x = s_c[0] + s_c[1] + s_c[2] + s_c[3];
        out2.y = s_m[0] + s_m[1] + s_m[2] + s_m[3];
        partial[b * NBLK_P + blockIdx.x] = out2;
    }
}

// One block, 256 threads: 8 threads per video reduce 64 partials each-strided,
// then per-video value, then mean over the 32 videos.
__global__ __launch_bounds__(256) void fcos_finalize_kernel(
    const float2* __restrict__ partial,  // [B, NBLK_P]
    float* __restrict__ out)             // [1]
{
    const int t = threadIdx.x;           // 0..255
    const int b = t >> 3;                // 0..31
    const int j = t & 7;                 // 0..7

    float s = 0.0f, n = 0.0f;
    #pragma unroll
    for (int k = j; k < NBLK_P; k += 8) {
        const float2 v = partial[b * NBLK_P + k];
        s += v.x;
        n += v.y;
    }
    // reduce within each contiguous 8-lane group (stays in-group: off<=4)
    #pragma unroll
    for (int off = 4; off > 0; off >>= 1) {
        s += __shfl_down(s, off, 64);
        n += __shfl_down(n, off, 64);
    }

    __shared__ float pv[B_SZ];
    if (j == 0) {
        pv[b] = (n > 0.0f) ? (2.0f * s / fmaxf(n, 1.0f)) : 0.0f;
    }
    __syncthreads();

    if (t < 64) {
        float v = (t < B_SZ) ? pv[t] : 0.0f;
        #pragma unroll
        for (int off = 16; off > 0; off >>= 1) v += __shfl_down(v, off, 64);
        if (t == 0) out[0] = v * (1.0f / (float)B_SZ);
    }
}

extern "C" void kernel_launch(void* const* d_in, const int* in_sizes, int n_in,
                              void* d_out, int out_size, void* d_ws, size_t ws_size,
                              hipStream_t stream) {
    const float* reg_preds = (const float*)d_in[0];   // [B, P, 2]
    const float* positions = (const float*)d_in[1];   // [B, P]
    const float* gt_boxes  = (const float*)d_in[2];   // [B, A, 2]
    const float* mi        = (const float*)d_in[3];   // [P, 2]
    float* out = (float*)d_out;
    float2* partial = (float2*)d_ws;                   // [B, NBLK_P] = 16 KB

    dim3 grid(NBLK_P, B_SZ);
    fcos_main_kernel<<<grid, 256, 0, stream>>>(reg_preds, positions, gt_boxes, mi, partial);
    fcos_finalize_kernel<<<1, 256, 0, stream>>>(partial, out);
}